// Round 6
// baseline (98.875 us; speedup 1.0000x reference)
//
#include <hip/hip_runtime.h>
#include <math.h>

typedef _Float16 v8h __attribute__((ext_vector_type(8)));
typedef float    v4f __attribute__((ext_vector_type(4)));

// LDS (53,888 B -> well under 2-blocks/CU budget, no A/B staging at all):
//  VT [0, 32768):      128 ch x 128 pos fp16, 256 B rows, XOR-swizzled 16B chunks
//                      pos 0..95 = halo (zero for OOB), 96..127 = tile pixels
//  L  [32768, 45568):  32 px x 100 fp32 (96 halo logit cols used; pad->bank spread)
//  P  [45568, 53760):  32 px x 128 fp16, swizzled (zero except 26 cols/row)
//  SL [53760, 53888):  32 fp32 self-logits (||main_px||^2)
#define VT_OFF  0
#define L_OFF   32768
#define P_OFF   45568
#define SL_OFF  53760
#define LDS_SZ  53888

__device__ __forceinline__ int swz(int r, int c16) {
    return (r << 8) + ((c16 ^ (r & 15)) << 4);
}

__global__ __launch_bounds__(512, 4) void local_attn_direct(
    const float* __restrict__ main_,
    const float* __restrict__ main_value,
    const float* __restrict__ ref,
    const float* __restrict__ ref_value,
    float* __restrict__ out)
{
    __shared__ __align__(16) char S[LDS_SZ];

    const int tid = threadIdx.x;
    const int bid = blockIdx.x;
    const int b  = bid >> 7;
    const int h0 = ((bid >> 3) & 15) << 2;   // 4-row tile
    const int w0 = (bid & 7) << 3;           // 8-col tile
    const int lane = tid & 63, w = tid >> 6;
    const int l15 = lane & 15, quad = lane >> 4;
    const int mt = w >> 2, wl = w & 3;       // m-tile group, role within group

    // zero P (softmax only writes 26 cols/row)
    *(uint4*)(S + P_OFF + tid * 16) = make_uint4(0, 0, 0, 0);

    // ===== epoch 1a: VT staging (coalesced global -> LDS transpose) =====
    // 32 tasks (8 positions x 64 channels each), 4 per wave; load->cvt->write
    // per task keeps <=8 fp32 live (no spill).
    #pragma unroll
    for (int i = 0; i < 4; ++i) {
        const int tk = (w << 2) + i;              // 0..31
        const int pb = tk & 15;                   // position block (8 pos)
        const int ch = ((tk >> 4) << 6) + lane;   // channel 0..127
        float pvv[8];
        #pragma unroll
        for (int j = 0; j < 8; ++j) {
            const int pos = (pb << 3) + j;        // wave-uniform
            float v = 0.f;
            if (pos < 96) {
                const int hy = pos / 12, hx = pos - hy * 12;
                const int gh = h0 - 2 + hy, gw = w0 - 2 + hx;
                if ((gh >= 0) & (gh < 64) & (gw >= 0) & (gw < 64))
                    v = ref_value[(size_t)((((b << 6) + gh) << 6) + gw) * 128 + ch];
            } else {
                const int t2 = pos - 96;
                v = main_value[(size_t)((((b << 6) + h0 + (t2 >> 3)) << 6) + (w0 + (t2 & 7))) * 128 + ch];
            }
            pvv[j] = v;
        }
        v8h hv;
        #pragma unroll
        for (int j = 0; j < 8; ++j) hv[j] = (_Float16)pvv[j];
        *(v8h*)(S + VT_OFF + swz(ch, pb)) = hv;
    }

    // ===== epoch 1b: QK straight from global (no LDS staging) =====
    // A fragment: lane holds main[px = mt*16+l15][k = ks*32+quad*8 ..+7]
    v8h a[4];
    float sq = 0.f;
    {
        const int px = (mt << 4) + l15;
        const float* ap = main_ + (size_t)((((b << 6) + h0 + (px >> 3)) << 6) + (w0 + (px & 7))) * 128;
        #pragma unroll
        for (int ks = 0; ks < 4; ++ks) {
            const float4 v0 = *(const float4*)(ap + (ks << 5) + (quad << 3));
            const float4 v1 = *(const float4*)(ap + (ks << 5) + (quad << 3) + 4);
            const float a8[8] = {v0.x, v0.y, v0.z, v0.w, v1.x, v1.y, v1.z, v1.w};
            #pragma unroll
            for (int j = 0; j < 8; ++j) {
                a[ks][j] = (_Float16)a8[j];
                sq += a8[j] * a8[j];              // self logit = ||main_px||^2
            }
        }
        if (wl == 0) {                            // one wave per m-tile writes SL
            sq += __shfl_xor(sq, 16);
            sq += __shfl_xor(sq, 32);
            if (quad == 0) *(float*)(S + SL_OFF + (px << 2)) = sq;
        }
    }
    // B fragment: lane holds ref[halo row = nt*16+l15][same k]; OOB row -> 0
    // 6 n-tiles (96 halo cols) over 4 waves per m-group: wl -> {wl, wl+4(<6)}
    #pragma unroll
    for (int nn = 0; nn < 2; ++nn) {
        const int nt = wl + (nn << 2);
        if (nt < 6) {
            const int hr = (nt << 4) + l15;       // halo index 0..95
            const int hy = hr / 12, hx = hr - hy * 12;
            const int gh = h0 - 2 + hy, gw = w0 - 2 + hx;
            const bool ok = (gh >= 0) & (gh < 64) & (gw >= 0) & (gw < 64);
            const float* bp = ref + (size_t)((((b << 6) + (ok ? gh : 0)) << 6) + (ok ? gw : 0)) * 128;
            v4f acc = {0, 0, 0, 0};
            #pragma unroll
            for (int ks = 0; ks < 4; ++ks) {
                float4 v0 = make_float4(0, 0, 0, 0), v1 = v0;
                if (ok) {
                    v0 = *(const float4*)(bp + (ks << 5) + (quad << 3));
                    v1 = *(const float4*)(bp + (ks << 5) + (quad << 3) + 4);
                }
                const float b8[8] = {v0.x, v0.y, v0.z, v0.w, v1.x, v1.y, v1.z, v1.w};
                v8h bh;
                #pragma unroll
                for (int j = 0; j < 8; ++j) bh[j] = (_Float16)b8[j];
                acc = __builtin_amdgcn_mfma_f32_16x16x32_f16(a[ks], bh, acc, 0, 0, 0);
            }
            // C layout: col(n) = l15 -> halo col, row(m) = quad*4+j -> px
            #pragma unroll
            for (int j = 0; j < 4; ++j) {
                const int px = (mt << 4) + (quad << 2) + j;
                *(float*)(S + L_OFF + px * 400 + (((nt << 4) + l15) << 2)) = acc[j];
            }
        }
    }
    __syncthreads();

    // ===== epoch 2: softmax -> P (2 px per 32-lane half, 4 px per wave) =====
    {
        const int half = lane >> 5, l = lane & 31;
        #pragma unroll
        for (int it = 0; it < 2; ++it) {
            const int t = (w << 2) + (it << 1) + half;
            const int ty = t >> 3, tx = t & 7;
            const bool act = l < 26;
            int col = 0;
            float lg = -INFINITY;
            if (l < 25) {
                const int dy = l / 5 - 2, dx = l % 5 - 2;
                col = (ty + dy + 2) * 12 + (tx + dx + 2);
                lg = *(const float*)(S + L_OFF + t * 400 + (col << 2));   // OOB cols hold 0
            } else if (l == 25) {
                col = 96 + t;                                             // self position
                lg = *(const float*)(S + SL_OFF + (t << 2));
            }
            float m = lg;
            #pragma unroll
            for (int off = 16; off; off >>= 1) m = fmaxf(m, __shfl_xor(m, off));
            const float e = act ? __expf(lg - m) : 0.f;
            float s = e;
            #pragma unroll
            for (int off = 16; off; off >>= 1) s += __shfl_xor(s, off);
            if (act)
                *(_Float16*)(S + P_OFF + swz(t, col >> 3) + ((col & 7) << 1)) = (_Float16)(e / s);
        }
    }
    __syncthreads();

    // ===== epoch 3: O = P * VT via MFMA, store =====
    {
        const int ntp = wl << 1;                  // 2 channel n-tiles per wave
        const int prow = (mt << 4) + l15;
        const int v0r = (ntp << 4) + l15, v1r = v0r + 16;
        v4f acc0 = {0, 0, 0, 0}, acc1 = {0, 0, 0, 0};
        #pragma unroll
        for (int ks = 0; ks < 4; ++ks) {
            const int c16 = (ks << 2) + quad;
            const v8h pa  = *(const v8h*)(S + P_OFF  + swz(prow, c16));
            const v8h vt0 = *(const v8h*)(S + VT_OFF + swz(v0r,  c16));
            const v8h vt1 = *(const v8h*)(S + VT_OFF + swz(v1r,  c16));
            acc0 = __builtin_amdgcn_mfma_f32_16x16x32_f16(pa, vt0, acc0, 0, 0, 0);
            acc1 = __builtin_amdgcn_mfma_f32_16x16x32_f16(pa, vt1, acc1, 0, 0, 0);
        }
        #pragma unroll
        for (int j = 0; j < 4; ++j) {
            const int px = (mt << 4) + (quad << 2) + j;
            const size_t gbase =
                (size_t)((((b << 6) + h0 + (px >> 3)) << 6) + (w0 + (px & 7))) * 128;
            out[gbase + ((ntp    ) << 4) + l15] = acc0[j];
            out[gbase + ((ntp + 1) << 4) + l15] = acc1[j];
        }
    }
}

extern "C" void kernel_launch(void* const* d_in, const int* in_sizes, int n_in,
                              void* d_out, int out_size, void* d_ws, size_t ws_size,
                              hipStream_t stream) {
    const float* main_      = (const float*)d_in[0];
    const float* main_value = (const float*)d_in[1];
    const float* ref        = (const float*)d_in[2];
    const float* ref_value  = (const float*)d_in[3];
    float* out = (float*)d_out;

    dim3 grid(4 * 16 * 8), block(512);   // 512 blocks (4x8 px tiles), 2 blocks/CU
    local_attn_direct<<<grid, block, 0, stream>>>(main_, main_value, ref, ref_value, out);
}